// Round 7
// baseline (284.548 us; speedup 1.0000x reference)
//
#include <hip/hip_runtime.h>
#include <math.h>

#define BB 64
#define RR 6912
#define II 8
#define CC 10
#define OO 16
#define RPB 32          // routes per block (chunk)
#define NCH 216         // RR / RPB
#define NIT 4           // iters per chunk; each iter covers 8 routes (4 waves x 2 rr)
#define LDSF (4*32*36)  // epilogue floats (18432 B); W tile (2 KB) aliases this

typedef _Float16 h2 __attribute__((ext_vector_type(2)));
union HV { int4 v; h2 h[4]; };

// ---------------- transpose+cvt kernel: x[B][R][8] f32 -> xth[R][B][8] f16 ----------------
__global__ __launch_bounds__(256) void transpose_cvt_kernel(
    const float* __restrict__ x, int4* __restrict__ xth4)
{
    __shared__ float4 lds4[64 * 34];
    const int rblk = blockIdx.x >> 2;
    const int bblk = blockIdx.x & 3;
    const int r0 = rblk * 64, b0 = bblk * 16;
    const int t = threadIdx.x;
    {
        const int rl = t & 63;
        const int bl0 = t >> 6;
#pragma unroll
        for (int kb = 0; kb < 4; ++kb) {
            const int bl = kb * 4 + bl0;
            const float4* src = (const float4*)(x + ((size_t)(b0 + bl) * RR + (r0 + rl)) * II);
            lds4[rl * 34 + bl * 2 + 0] = src[0];
            lds4[rl * 34 + bl * 2 + 1] = src[1];
        }
    }
    __syncthreads();
    {
        const int bl = t & 15;
        const int rw0 = t >> 4;
#pragma unroll
        for (int kr = 0; kr < 4; ++kr) {
            const int rw = kr * 16 + rw0;
            float4 a = lds4[rw * 34 + bl * 2 + 0];
            float4 bq = lds4[rw * 34 + bl * 2 + 1];
            HV u;
            u.h[0] = h2{(_Float16)a.x,  (_Float16)a.y};
            u.h[1] = h2{(_Float16)a.z,  (_Float16)a.w};
            u.h[2] = h2{(_Float16)bq.x, (_Float16)bq.y};
            u.h[3] = h2{(_Float16)bq.z, (_Float16)bq.w};
            xth4[(size_t)(r0 + rw) * BB + (b0 + bl)] = u.v;
        }
    }
}

// ---------------- W convert kernel: W[c][r][i][o] f32 -> wh[c][r][o][i] f16 ----------------
// One block per 8 routes (grid = C*RR/8). Coalesced float4 read, LDS b16
// scatter-transpose, coalesced b128 write.
__global__ __launch_bounds__(256) void wcvt_kernel(
    const float4* __restrict__ w4, int4* __restrict__ wh4)
{
    __shared__ __align__(16) _Float16 wl[1024];
    const int blk = blockIdx.x;            // c*864 + rb
    const int t = threadIdx.x;
    const float4 v = w4[(size_t)blk * 256 + t];
    const int rp = t >> 5;                 // route in 8-block
    const int i  = (t >> 2) & 7;
    const int o0 = (t & 3) * 4;
    wl[(rp * 16 + o0 + 0) * 8 + i] = (_Float16)v.x;
    wl[(rp * 16 + o0 + 1) * 8 + i] = (_Float16)v.y;
    wl[(rp * 16 + o0 + 2) * 8 + i] = (_Float16)v.z;
    wl[(rp * 16 + o0 + 3) * 8 + i] = (_Float16)v.w;
    __syncthreads();
    if (t < 128) wh4[(size_t)blk * 128 + t] = ((const int4*)wl)[t];
}

// ---------------- pass kernel ----------------
// Wave wv covers routes r0+wv*2+{0,1} (rr = lane>>5); each thread handles
// batches bg and bg+32 (bg = lane&31). W tile (8 routes, f16 [o][i]) staged
// LDS via 2 coalesced b128 wave-loads; compute via v_dot2_f32_f16.
// Partials accumulated into global sacc/sz via atomicAdd (no combine pass).
// No max-subtraction in softmax (|logit| small; validated R5/R6).
template <int MODE>
__global__ __launch_bounds__(256, 2) void pass_kernel(
    const int4* __restrict__ xth4, const int4* __restrict__ wh4,
    const float* __restrict__ ov_in,
    float* __restrict__ sacc, float* __restrict__ sz)
{
    __shared__ __align__(16) float lds[LDSF];
    int4* wlds = (int4*)lds;           // 128 int4 = 8 routes x 16 o x (8 i f16)

    const int bid = blockIdx.x;
    const int c = bid / NCH;
    const int chunk = bid - c * NCH;
    const int t = threadIdx.x;
    const int wv = t >> 6;
    const int lane = t & 63;
    const int rr = lane >> 5;
    const int bg = lane & 31;

    float acc0[OO], acc1[OO];
#pragma unroll
    for (int o = 0; o < OO; ++o) { acc0[o] = 0.f; acc1[o] = 0.f; }
    float Z0 = 0.f, Z1 = 0.f;

    float ov0[OO], ov1[OO];
    if (MODE != 0) {
        const float4* opa = (const float4*)(ov_in + ((size_t)c * BB + bg) * OO);
        const float4* opb = (const float4*)(ov_in + ((size_t)c * BB + bg + 32) * OO);
#pragma unroll
        for (int q = 0; q < 4; ++q) {
            float4 va = opa[q], vb = opb[q];
            ov0[q*4+0]=va.x; ov0[q*4+1]=va.y; ov0[q*4+2]=va.z; ov0[q*4+3]=va.w;
            ov1[q*4+0]=vb.x; ov1[q*4+1]=vb.y; ov1[q*4+2]=vb.z; ov1[q*4+3]=vb.w;
        }
    }

#pragma unroll 1
    for (int it = 0; it < NIT; ++it) {
        const int r0 = chunk * RPB + it * 8;
        __syncthreads();
        if (t < 128)
            wlds[t] = wh4[(size_t)(c * (RR / 8) + chunk * 4 + it) * 128 + t];
        __syncthreads();

        const int r = r0 + wv * 2 + rr;
        HV xa, xb;
        xa.v = xth4[(size_t)r * BB + bg];
        xb.v = xth4[(size_t)r * BB + bg + 32];

        float p0[OO], p1[OO];
#pragma unroll
        for (int o = 0; o < OO; ++o) {
            HV wq; wq.v = wlds[(wv * 2 + rr) * 16 + o];
            float a = __builtin_amdgcn_fdot2(xa.h[0], wq.h[0],
                        (MODE == 0) ? acc0[o] : 0.f, false);
            a = __builtin_amdgcn_fdot2(xa.h[1], wq.h[1], a, false);
            a = __builtin_amdgcn_fdot2(xa.h[2], wq.h[2], a, false);
            a = __builtin_amdgcn_fdot2(xa.h[3], wq.h[3], a, false);
            float bb = __builtin_amdgcn_fdot2(xb.h[0], wq.h[0],
                        (MODE == 0) ? acc1[o] : 0.f, false);
            bb = __builtin_amdgcn_fdot2(xb.h[1], wq.h[1], bb, false);
            bb = __builtin_amdgcn_fdot2(xb.h[2], wq.h[2], bb, false);
            bb = __builtin_amdgcn_fdot2(xb.h[3], wq.h[3], bb, false);
            if (MODE == 0) { acc0[o] = a; acc1[o] = bb; }
            else           { p0[o] = a;   p1[o] = bb; }
        }

        if (MODE != 0) {
            float d0 = 0.f, d1 = 0.f;
#pragma unroll
            for (int o = 0; o < OO; ++o) { d0 = fmaf(p0[o], ov0[o], d0); d1 = fmaf(p1[o], ov1[o], d1); }
            const float e0 = __expf(d0), e1 = __expf(d1);
            Z0 += e0; Z1 += e1;
#pragma unroll
            for (int o = 0; o < OO; ++o) { acc0[o] = fmaf(e0, p0[o], acc0[o]); acc1[o] = fmaf(e1, p1[o], acc1[o]); }
        }
    }

    // reduce across rr (lane ^ 32): sums the two routes of this wave
#pragma unroll
    for (int o = 0; o < OO; ++o) {
        acc0[o] += __shfl_xor(acc0[o], 32);
        acc1[o] += __shfl_xor(acc1[o], 32);
    }
    if (MODE != 0) { Z0 += __shfl_xor(Z0, 32); Z1 += __shfl_xor(Z1, 32); }

    __syncthreads();
    if (rr == 0) {
        float* s = lds + (wv * 32 + bg) * 36;
#pragma unroll
        for (int o = 0; o < OO; ++o) { s[o] = acc0[o]; s[16 + o] = acc1[o]; }
        s[32] = Z0; s[33] = Z1;
    }
    __syncthreads();

    // final block reduce -> atomic accumulate: thread t -> (b = t>>2, q = t&3)
    {
        const int b = t >> 2, q = t & 3;
        const int k = b >> 5, bgf = b & 31;
        float4 sum = make_float4(0.f, 0.f, 0.f, 0.f);
#pragma unroll
        for (int w2 = 0; w2 < 4; ++w2) {
            const float4 v = *(const float4*)(lds + (w2 * 32 + bgf) * 36 + k * 16 + q * 4);
            sum.x += v.x; sum.y += v.y; sum.z += v.z; sum.w += v.w;
        }
        float* dst = sacc + ((size_t)(c * BB + b)) * OO + q * 4;
        atomicAdd(dst + 0, sum.x);
        atomicAdd(dst + 1, sum.y);
        atomicAdd(dst + 2, sum.z);
        atomicAdd(dst + 3, sum.w);
        if (MODE != 0 && q == 0) {
            float z = 0.f;
#pragma unroll
            for (int w2 = 0; w2 < 4; ++w2) z += lds[(w2 * 32 + bgf) * 36 + 32 + k];
            atomicAdd(&sz[c * BB + b], z);
        }
    }
}

// ---------------- squash kernel ----------------
// 40 blocks x 256 threads, one thread per (c,b,o).
// MODE 0: out0 = squash(sacc/R); MODE 1: outsum = out0 + squash(sacc/Z);
// MODE 2: final = squash(sacc/Z)
template <int MODE>
__global__ __launch_bounds__(256) void squash_kernel(
    const float* __restrict__ sacc, const float* __restrict__ sz,
    const float* __restrict__ out0, float* __restrict__ outw)
{
    const int idx = blockIdx.x * 256 + threadIdx.x;   // < 10240
    const int cb = idx >> 4;
    float s = sacc[idx];
    if (MODE != 0) s /= sz[cb];
    else           s *= (1.0f / RR);
    float sq = s * s;
#pragma unroll
    for (int w = 1; w < 16; w <<= 1) sq += __shfl_xor(sq, w);
    float val = s * sqrtf(sq) / (1.f + sq);
    if (MODE == 1) val += out0[idx];
    outw[idx] = val;
}

extern "C" void kernel_launch(void* const* d_in, const int* in_sizes, int n_in,
                              void* d_out, int out_size, void* d_ws, size_t ws_size,
                              hipStream_t stream)
{
    const float* x = (const float*)d_in[0];
    const float* w = (const float*)d_in[1];
    float* out = (float*)d_out;

    float* ws = (float*)d_ws;
    float* xth    = ws;                                   // RR*BB*8 f16 = RR*BB*4 f32 slots
    float* wh     = xth + (size_t)RR * BB * 4;            // CC*RR*128 f16 = CC*RR*64 f32 slots
    float* sbuf   = wh + (size_t)CC * RR * 64;            // zeroed region:
    float* sacc0  = sbuf;                                 //   3 x CC*BB*OO
    float* sacc1  = sacc0 + CC * BB * OO;
    float* sacc2  = sacc1 + CC * BB * OO;
    float* sz0    = sacc2 + CC * BB * OO;                 //   3 x CC*BB
    float* sz1    = sz0 + CC * BB;
    float* sz2    = sz1 + CC * BB;
    float* out0   = sz2 + CC * BB;                        // CC*BB*OO
    float* outsum = out0 + CC * BB * OO;                  // CC*BB*OO

    int4* xth4 = (int4*)xth;
    int4* wh4  = (int4*)wh;
    const float4* w4 = (const float4*)w;

    // zero the atomic accumulators (graph-capturable stream op)
    hipMemsetAsync(sbuf, 0, (size_t)(3 * CC * BB * OO + 3 * CC * BB) * sizeof(float), stream);

    transpose_cvt_kernel<<<dim3((RR / 64) * 4), dim3(256), 0, stream>>>(x, xth4);
    wcvt_kernel<<<dim3(CC * (RR / 8)), dim3(256), 0, stream>>>(w4, wh4);

    const dim3 gp(CC * NCH), bp(256);
    const dim3 gs(CC * BB * OO / 256), bs(256);

    pass_kernel<0><<<gp, bp, 0, stream>>>(xth4, wh4, nullptr, sacc0, sz0);
    squash_kernel<0><<<gs, bs, 0, stream>>>(sacc0, sz0, nullptr, out0);
    pass_kernel<1><<<gp, bp, 0, stream>>>(xth4, wh4, out0, sacc1, sz1);
    squash_kernel<1><<<gs, bs, 0, stream>>>(sacc1, sz1, out0, outsum);
    pass_kernel<2><<<gp, bp, 0, stream>>>(xth4, wh4, outsum, sacc2, sz2);
    squash_kernel<2><<<gs, bs, 0, stream>>>(sacc2, sz2, nullptr, out);
}

// Round 8
// 166.871 us; speedup vs baseline: 1.7052x; 1.7052x over previous
//
#include <hip/hip_runtime.h>
#include <math.h>

#define BB 64
#define RR 6912
#define II 8
#define CC 10
#define OO 16
#define RPB 64          // routes per block (chunk)
#define NCH 108         // RR / RPB
#define NIT 8           // iters per chunk; each iter covers 8 routes (4 waves x 2 rr)
#define LDSF 4608       // floats; W tile (64 routes x 256 B = 16 KB) aliases epilogue (18 KB)

typedef _Float16 h2 __attribute__((ext_vector_type(2)));
union HV { int4 v; h2 h[4]; };

// ---------------- transpose+cvt kernel: x[B][R][8] f32 -> xth[R][B][8] f16 ----------------
__global__ __launch_bounds__(256) void transpose_cvt_kernel(
    const float* __restrict__ x, int4* __restrict__ xth4)
{
    __shared__ float4 lds4[64 * 34];
    const int rblk = blockIdx.x >> 2;
    const int bblk = blockIdx.x & 3;
    const int r0 = rblk * 64, b0 = bblk * 16;
    const int t = threadIdx.x;
    {
        const int rl = t & 63;
        const int bl0 = t >> 6;
#pragma unroll
        for (int kb = 0; kb < 4; ++kb) {
            const int bl = kb * 4 + bl0;
            const float4* src = (const float4*)(x + ((size_t)(b0 + bl) * RR + (r0 + rl)) * II);
            lds4[rl * 34 + bl * 2 + 0] = src[0];
            lds4[rl * 34 + bl * 2 + 1] = src[1];
        }
    }
    __syncthreads();
    {
        const int bl = t & 15;
        const int rw0 = t >> 4;
#pragma unroll
        for (int kr = 0; kr < 4; ++kr) {
            const int rw = kr * 16 + rw0;
            float4 a = lds4[rw * 34 + bl * 2 + 0];
            float4 bq = lds4[rw * 34 + bl * 2 + 1];
            HV u;
            u.h[0] = h2{(_Float16)a.x,  (_Float16)a.y};
            u.h[1] = h2{(_Float16)a.z,  (_Float16)a.w};
            u.h[2] = h2{(_Float16)bq.x, (_Float16)bq.y};
            u.h[3] = h2{(_Float16)bq.z, (_Float16)bq.w};
            xth4[(size_t)(r0 + rw) * BB + (b0 + bl)] = u.v;
        }
    }
}

// ---------------- W convert kernel: W[c][r][i][o] f32 -> wh[c][r][o][i] f16 ----------------
__global__ __launch_bounds__(256) void wcvt_kernel(
    const float4* __restrict__ w4, int4* __restrict__ wh4)
{
    __shared__ __align__(16) _Float16 wl[1024];
    const int blk = blockIdx.x;            // c*864 + rb (8 routes per block)
    const int t = threadIdx.x;
    const float4 v = w4[(size_t)blk * 256 + t];
    const int rp = t >> 5;
    const int i  = (t >> 2) & 7;
    const int o0 = (t & 3) * 4;
    wl[(rp * 16 + o0 + 0) * 8 + i] = (_Float16)v.x;
    wl[(rp * 16 + o0 + 1) * 8 + i] = (_Float16)v.y;
    wl[(rp * 16 + o0 + 2) * 8 + i] = (_Float16)v.z;
    wl[(rp * 16 + o0 + 3) * 8 + i] = (_Float16)v.w;
    __syncthreads();
    if (t < 128) wh4[(size_t)blk * 128 + t] = ((const int4*)wl)[t];
}

// ---------------- pass kernel ----------------
// Stages the block's FULL 64-route W tile (f16 [r][o][i], 16 KB) once, then a
// barrier-free main loop: wave wv covers routes it*8+wv*2+{0,1} (rr=lane>>5),
// each thread handles batches bg and bg+32. dot2 f16 compute, f32 accumulate.
// No max-subtraction in softmax (|logit| small; validated R5-R7).
template <int MODE>
__global__ __launch_bounds__(256, 4) void pass_kernel(
    const int4* __restrict__ xth4, const int4* __restrict__ wh4,
    const float* __restrict__ ov_in,
    float* __restrict__ pacc, float* __restrict__ pz)
{
    __shared__ __align__(16) float lds[LDSF];
    int4* wlds = (int4*)lds;           // 1024 int4 = 64 routes x 16 o x (8 i f16)

    const int bid = blockIdx.x;
    const int c = bid / NCH;
    const int chunk = bid - c * NCH;
    const int t = threadIdx.x;
    const int wv = t >> 6;
    const int lane = t & 63;
    const int rr = lane >> 5;
    const int bg = lane & 31;

    // stage all 64 routes' W once: 256 threads x 4 int4, coalesced
    {
        const int4* src = wh4 + (size_t)(c * (RR / 8) + chunk * 8) * 128;
#pragma unroll
        for (int k = 0; k < 4; ++k) wlds[k * 256 + t] = src[k * 256 + t];
    }

    float acc0[OO], acc1[OO];
#pragma unroll
    for (int o = 0; o < OO; ++o) { acc0[o] = 0.f; acc1[o] = 0.f; }
    float Z0 = 0.f, Z1 = 0.f;

    float ov0[OO], ov1[OO];
    if (MODE != 0) {
        const float4* opa = (const float4*)(ov_in + ((size_t)c * BB + bg) * OO);
        const float4* opb = (const float4*)(ov_in + ((size_t)c * BB + bg + 32) * OO);
#pragma unroll
        for (int q = 0; q < 4; ++q) {
            float4 va = opa[q], vb = opb[q];
            ov0[q*4+0]=va.x; ov0[q*4+1]=va.y; ov0[q*4+2]=va.z; ov0[q*4+3]=va.w;
            ov1[q*4+0]=vb.x; ov1[q*4+1]=vb.y; ov1[q*4+2]=vb.z; ov1[q*4+3]=vb.w;
        }
    }

    __syncthreads();   // W tile ready; no further barriers until epilogue

#pragma unroll 1
    for (int it = 0; it < NIT; ++it) {
        const int rl = it * 8 + wv * 2 + rr;        // route within tile
        const int r  = chunk * RPB + rl;            // global route
        HV xa, xb;
        xa.v = xth4[(size_t)r * BB + bg];
        xb.v = xth4[(size_t)r * BB + bg + 32];

        float p0[OO], p1[OO];
#pragma unroll
        for (int o = 0; o < OO; ++o) {
            HV wq; wq.v = wlds[rl * 16 + o];
            float a = __builtin_amdgcn_fdot2(xa.h[0], wq.h[0],
                        (MODE == 0) ? acc0[o] : 0.f, false);
            a = __builtin_amdgcn_fdot2(xa.h[1], wq.h[1], a, false);
            a = __builtin_amdgcn_fdot2(xa.h[2], wq.h[2], a, false);
            a = __builtin_amdgcn_fdot2(xa.h[3], wq.h[3], a, false);
            float bb = __builtin_amdgcn_fdot2(xb.h[0], wq.h[0],
                        (MODE == 0) ? acc1[o] : 0.f, false);
            bb = __builtin_amdgcn_fdot2(xb.h[1], wq.h[1], bb, false);
            bb = __builtin_amdgcn_fdot2(xb.h[2], wq.h[2], bb, false);
            bb = __builtin_amdgcn_fdot2(xb.h[3], wq.h[3], bb, false);
            if (MODE == 0) { acc0[o] = a; acc1[o] = bb; }
            else           { p0[o] = a;   p1[o] = bb; }
        }

        if (MODE != 0) {
            float d0 = 0.f, d1 = 0.f;
#pragma unroll
            for (int o = 0; o < OO; ++o) { d0 = fmaf(p0[o], ov0[o], d0); d1 = fmaf(p1[o], ov1[o], d1); }
            const float e0 = __expf(d0), e1 = __expf(d1);
            Z0 += e0; Z1 += e1;
#pragma unroll
            for (int o = 0; o < OO; ++o) { acc0[o] = fmaf(e0, p0[o], acc0[o]); acc1[o] = fmaf(e1, p1[o], acc1[o]); }
        }
    }

    // reduce across rr (lane ^ 32): sums the two routes of this wave
#pragma unroll
    for (int o = 0; o < OO; ++o) {
        acc0[o] += __shfl_xor(acc0[o], 32);
        acc1[o] += __shfl_xor(acc1[o], 32);
    }
    if (MODE != 0) { Z0 += __shfl_xor(Z0, 32); Z1 += __shfl_xor(Z1, 32); }

    __syncthreads();   // done reading W tile; LDS reused for merge
    if (rr == 0) {
        float* s = lds + (wv * 32 + bg) * 36;
#pragma unroll
        for (int o = 0; o < OO; ++o) { s[o] = acc0[o]; s[16 + o] = acc1[o]; }
        s[32] = Z0; s[33] = Z1;
    }
    __syncthreads();

    // final block reduce: thread t -> (b = t>>2, o-quad q = t&3)
    {
        const int b = t >> 2, q = t & 3;
        const int k = b >> 5, bgf = b & 31;
        float4 sum = make_float4(0.f, 0.f, 0.f, 0.f);
#pragma unroll
        for (int w2 = 0; w2 < 4; ++w2) {
            const float4 v = *(const float4*)(lds + (w2 * 32 + bgf) * 36 + k * 16 + q * 4);
            sum.x += v.x; sum.y += v.y; sum.z += v.z; sum.w += v.w;
        }
        *(float4*)(pacc + (((size_t)(c * NCH + chunk) * BB + b) * OO) + q * 4) = sum;
        if (MODE != 0 && q == 0) {
            float z = 0.f;
#pragma unroll
            for (int w2 = 0; w2 < 4; ++w2) z += lds[(w2 * 32 + bgf) * 36 + 32 + k];
            pz[(size_t)(c * NCH + chunk) * BB + b] = z;
        }
    }
}

// ---------------- combine kernel ----------------
// One block per (c,b). 256 threads = 16 o x 16 groups. Plain sums (no max).
template <int MODE>
__global__ __launch_bounds__(256) void combine_kernel(
    const float* __restrict__ pacc, const float* __restrict__ pz,
    const float* __restrict__ out0, float* __restrict__ outw)
{
    __shared__ float lsum[256];
    __shared__ float lz[16];
    const int cb = blockIdx.x;
    const int c = cb >> 6, b = cb & 63;
    const int t = threadIdx.x;
    const int o = t & 15, g = t >> 4;

    float s = 0.f, zl = 0.f;
    for (int p = g; p < NCH; p += 16) {
        s += pacc[((size_t)(c * NCH + p) * BB + b) * OO + o];
        if (MODE != 0 && o == 0) zl += pz[(size_t)(c * NCH + p) * BB + b];
    }
    lsum[t] = s;
    if (MODE != 0 && o == 0) lz[g] = zl;
    __syncthreads();

    if (g == 0) {
#pragma unroll
        for (int k = 1; k < 16; ++k) s += lsum[k * 16 + o];
        if (MODE != 0) {
            float Zt = 0.f;
#pragma unroll
            for (int k = 0; k < 16; ++k) Zt += lz[k];
            s /= Zt;
        } else {
            s *= (1.0f / RR);
        }
        float sq = s * s;
#pragma unroll
        for (int w = 1; w < 16; w <<= 1) sq += __shfl_xor(sq, w);
        float val = s * sqrtf(sq) / (1.f + sq);
        if (MODE == 1) val += out0[(size_t)cb * OO + o];
        outw[(size_t)cb * OO + o] = val;
    }
}

extern "C" void kernel_launch(void* const* d_in, const int* in_sizes, int n_in,
                              void* d_out, int out_size, void* d_ws, size_t ws_size,
                              hipStream_t stream)
{
    const float* x = (const float*)d_in[0];
    const float* w = (const float*)d_in[1];
    float* out = (float*)d_out;

    float* ws = (float*)d_ws;
    float* xth    = ws;                                   // RR*BB*8 f16 = RR*BB*4 f32 slots
    float* wh     = xth + (size_t)RR * BB * 4;            // CC*RR*128 f16 = CC*RR*64 f32 slots
    float* pacc   = wh + (size_t)CC * RR * 64;            // CC*NCH*BB*OO
    float* pz     = pacc + (size_t)CC * NCH * BB * OO;    // CC*NCH*BB
    float* out0   = pz + (size_t)CC * NCH * BB;           // CC*BB*OO
    float* outsum = out0 + CC * BB * OO;                  // CC*BB*OO

    int4* xth4 = (int4*)xth;
    int4* wh4  = (int4*)wh;
    const float4* w4 = (const float4*)w;

    transpose_cvt_kernel<<<dim3((RR / 64) * 4), dim3(256), 0, stream>>>(x, xth4);
    wcvt_kernel<<<dim3(CC * (RR / 8)), dim3(256), 0, stream>>>(w4, wh4);

    const dim3 gp(CC * NCH), bp(256);
    const dim3 gc(CC * BB), bc(256);

    pass_kernel<0><<<gp, bp, 0, stream>>>(xth4, wh4, nullptr, pacc, pz);
    combine_kernel<0><<<gc, bc, 0, stream>>>(pacc, pz, nullptr, out0);
    pass_kernel<1><<<gp, bp, 0, stream>>>(xth4, wh4, out0, pacc, pz);
    combine_kernel<1><<<gc, bc, 0, stream>>>(pacc, pz, out0, outsum);
    pass_kernel<2><<<gp, bp, 0, stream>>>(xth4, wh4, outsum, pacc, pz);
    combine_kernel<2><<<gc, bc, 0, stream>>>(pacc, pz, nullptr, out);
}